// Round 6
// baseline (400.056 us; speedup 1.0000x reference)
//
#include <hip/hip_runtime.h>

// LSTM B=4096, T=512, I=1, H=64, O=1 (fp32 in/out).
// Round 6: DUAL-GROUP blocks. 256 thr (4 waves) handle TWO independent
// 8-batch groups (16 batches/block, grid=256, ~1 block/CU). Both groups share
// the Bf weight registers and ONE barrier/step; their MFMA/trans chains are
// independent -> in-stream ILP hides each other's latency (r4's 590 idle
// cyc/step came from 2 lockstep blocks failing to do this).
// Per group (= r4 structure, busy-minimal): hi/lo of h packed into M
// (row 2q=hi, 2q+1=lo of batch q), 8 MFMA/wave-step, all 4 gates of a cell
// colocated in one lane's acc regs (2 cells/lane), zero shuffles.
// MFMA layouts (m89-verified): A[m=lane&15][k=(lane>>4)*8+i],
// B[k=(lane>>4)*8+i][n=lane&15], D[m=(lane>>4)*4+r][n=lane&15].

#define TT   512
#define HP   72            // f16 row stride (144 B): 16B-aligned, 2-way max
#define BUFE (16 * HP)     // one ping-pong buffer: 16 rows
#define SXP  17            // sh_x row stride (floats), odd -> spread banks

typedef _Float16 f16x8 __attribute__((ext_vector_type(8)));
typedef float    f32x4 __attribute__((ext_vector_type(4)));

#define MFMA16(a, b, c) __builtin_amdgcn_mfma_f32_16x16x32_f16((a), (b), (c), 0, 0, 0)

__device__ __forceinline__ float rcp_(float x) { return __builtin_amdgcn_rcpf(x); }
__device__ __forceinline__ float sigmoid_(float x) { return rcp_(1.0f + __expf(-x)); }
__device__ __forceinline__ float tanh_(float x) { return 1.0f - 2.0f * rcp_(1.0f + __expf(2.0f * x)); }

__device__ __forceinline__ f16x8 cvt8(const float4& u0, const float4& u1) {
    f16x8 r;
    r[0] = (_Float16)u0.x; r[1] = (_Float16)u0.y; r[2] = (_Float16)u0.z; r[3] = (_Float16)u0.w;
    r[4] = (_Float16)u1.x; r[5] = (_Float16)u1.y; r[6] = (_Float16)u1.z; r[7] = (_Float16)u1.w;
    return r;
}

__global__ __launch_bounds__(256, 1) void lstm_mfma(
    const float* __restrict__ x,      // [4096, 512]
    const float* __restrict__ w_ih,   // [256]
    const float* __restrict__ w_hh,   // [256, 64]
    const float* __restrict__ b_ih,   // [256]
    const float* __restrict__ b_hh,   // [256]
    const float* __restrict__ w_out,  // [64]
    const float* __restrict__ b_out,  // [1]
    float* __restrict__ out)          // [4096]
{
    __shared__ __align__(16) float    sh_x[TT * SXP];     // [t][m16], 34.8 KB
    __shared__ __align__(16) _Float16 hbuf[2][2][BUFE];   // [group][pp][..], 9.2 KB

    const int tid = threadIdx.x;
    const int w   = tid >> 6;    // wave 0..3 (owns N-tiles {w, w+4, w+8, w+12})
    const int L   = tid & 63;
    const int l16 = L & 15;
    const int h0  = L >> 4;      // 0..3
    const int b0  = blockIdx.x * 16;
    const int j   = 16 * w + l16;  // hidden unit col owned by this lane

    // ---- stage x: sh_x[t*SXP + m] = x[b0+m][t], m=0..15 (float4 coalesced) ----
    {
        const int half = tid >> 7;       // 0..1
        const int l    = tid & 127;
        const int t0   = 4 * l;
        #pragma unroll
        for (int q8 = 0; q8 < 8; ++q8) {
            const int q = q8 + 8 * half;
            float4 v = *(const float4*)(x + (size_t)(b0 + q) * TT + t0);
            sh_x[(t0 + 0) * SXP + q] = v.x;
            sh_x[(t0 + 1) * SXP + q] = v.y;
            sh_x[(t0 + 2) * SXP + q] = v.z;
            sh_x[(t0 + 3) * SXP + q] = v.w;
        }
    }
    // ---- zero all h buffers ----
    for (int i = tid; i < 2 * 2 * BUFE; i += 256) (&hbuf[0][0][0])[i] = (_Float16)0.0f;

    // ---- preload W_hh fragments (fp16-rounded once) ----
    f16x8 Bf[4][2];
    float wihv[4], biasv[4];
    #pragma unroll
    for (int s = 0; s < 4; ++s) {
        const int n = 64 * s + j;
        #pragma unroll
        for (int kt = 0; kt < 2; ++kt) {
            const float* p = w_hh + n * 64 + kt * 32 + h0 * 8;
            float4 u0 = *(const float4*)p;
            float4 u1 = *(const float4*)(p + 4);
            Bf[s][kt] = cvt8(u0, u1);
        }
        wihv[s]  = w_ih[n];
        biasv[s] = b_ih[n] + b_hh[n];
    }

    // lane's cells per group: batches q=2h0, 2h0+1; A-frag row l16; writes
    // rows 4h0..4h0+3 (hi/lo of both batches), col j.
    const int aoff = l16 * HP + h0 * 8;   // f16 units; +32 for K-chunk 1
    const int wr0  = (4 * h0) * HP + j;

    float cc[2][2] = {{0.0f, 0.0f}, {0.0f, 0.0f}};
    __syncthreads();

    auto step = [&](int pp, int t) {
        const _Float16* rb0 = hbuf[0][pp];
        const _Float16* rb1 = hbuf[1][pp];
        _Float16* wb[2] = { hbuf[0][pp ^ 1], hbuf[1][pp ^ 1] };

        // ---- A fragments, both groups (independent ds_reads) ----
        f16x8 A00 = *(const f16x8*)(rb0 + aoff);
        f16x8 A01 = *(const f16x8*)(rb0 + aoff + 32);
        f16x8 A10 = *(const f16x8*)(rb1 + aoff);
        f16x8 A11 = *(const f16x8*)(rb1 + aoff + 32);

        const f32x4 z = {0.f, 0.f, 0.f, 0.f};
        f32x4 acc[2][4];
        #pragma unroll
        for (int s = 0; s < 4; ++s)
            acc[0][s] = MFMA16(A01, Bf[s][1], MFMA16(A00, Bf[s][0], z));
        #pragma unroll
        for (int s = 0; s < 4; ++s)
            acc[1][s] = MFMA16(A11, Bf[s][1], MFMA16(A10, Bf[s][0], z));

        // ---- activations: 2 groups x 2 cells/lane, fully independent ----
        #pragma unroll
        for (int g = 0; g < 2; ++g) {
            const float2 xv = *(const float2*)(sh_x + t * SXP + 8 * g + 2 * h0);
            _Float16* wbg = wb[g];
            // cell 0: batch 2h0 (gate = acc[0]+acc[1])
            {
                float gi = (acc[g][0][0] + acc[g][0][1]) + fmaf(xv.x, wihv[0], biasv[0]);
                float gf = (acc[g][1][0] + acc[g][1][1]) + fmaf(xv.x, wihv[1], biasv[1]);
                float gg = (acc[g][2][0] + acc[g][2][1]) + fmaf(xv.x, wihv[2], biasv[2]);
                float go = (acc[g][3][0] + acc[g][3][1]) + fmaf(xv.x, wihv[3], biasv[3]);
                float i_ = sigmoid_(gi), f_ = sigmoid_(gf);
                float g_ = tanh_(gg),   o_ = sigmoid_(go);
                cc[g][0] = fmaf(f_, cc[g][0], i_ * g_);
                float hv = o_ * tanh_(cc[g][0]);
                _Float16 hh = (_Float16)hv;
                wbg[wr0]      = hh;
                wbg[wr0 + HP] = (_Float16)(hv - (float)hh);
            }
            // cell 1: batch 2h0+1 (gate = acc[2]+acc[3])
            {
                float gi = (acc[g][0][2] + acc[g][0][3]) + fmaf(xv.y, wihv[0], biasv[0]);
                float gf = (acc[g][1][2] + acc[g][1][3]) + fmaf(xv.y, wihv[1], biasv[1]);
                float gg = (acc[g][2][2] + acc[g][2][3]) + fmaf(xv.y, wihv[2], biasv[2]);
                float go = (acc[g][3][2] + acc[g][3][3]) + fmaf(xv.y, wihv[3], biasv[3]);
                float i_ = sigmoid_(gi), f_ = sigmoid_(gf);
                float g_ = tanh_(gg),   o_ = sigmoid_(go);
                cc[g][1] = fmaf(f_, cc[g][1], i_ * g_);
                float hv = o_ * tanh_(cc[g][1]);
                _Float16 hh = (_Float16)hv;
                wbg[wr0 + 2 * HP] = hh;
                wbg[wr0 + 3 * HP] = (_Float16)(hv - (float)hh);
            }
        }
        __syncthreads();
    };

    for (int t = 0; t < TT; t += 2) {
        step(0, t);
        step(1, t + 1);
    }

    // ---- epilogue: final h in pp=0; wave w reduces batches {w, w+4, w+8, w+12} ----
    const float wo = w_out[L];
    #pragma unroll
    for (int p = 0; p < 4; ++p) {
        const int m = w + 4 * p;          // block-local batch 0..15
        const int g = m >> 3, q = m & 7;
        float hvf = (float)hbuf[g][0][(2 * q) * HP + L]
                  + (float)hbuf[g][0][(2 * q + 1) * HP + L];
        float v = hvf * wo;
        #pragma unroll
        for (int off = 32; off; off >>= 1) v += __shfl_down(v, off);
        if (L == 0) out[b0 + m] = v + b_out[0];
    }
}

extern "C" void kernel_launch(void* const* d_in, const int* in_sizes, int n_in,
                              void* d_out, int out_size, void* d_ws, size_t ws_size,
                              hipStream_t stream) {
    const float* x     = (const float*)d_in[0];
    const float* w_ih  = (const float*)d_in[1];
    const float* w_hh  = (const float*)d_in[2];
    const float* b_ih  = (const float*)d_in[3];
    const float* b_hh  = (const float*)d_in[4];
    const float* w_out = (const float*)d_in[5];
    const float* b_out = (const float*)d_in[6];
    float* out = (float*)d_out;

    lstm_mfma<<<256, 256, 0, stream>>>(x, w_ih, w_hh, b_ih, b_hh,
                                       w_out, b_out, out);
}